// Round 10
// baseline (745.097 us; speedup 1.0000x reference)
//
#include <hip/hip_runtime.h>

#ifndef __has_builtin
#define __has_builtin(x) 0
#endif

typedef float v2f __attribute__((ext_vector_type(2)));

__device__ __forceinline__ float fexp2(float x) {
#if __has_builtin(__builtin_amdgcn_exp2f)
    return __builtin_amdgcn_exp2f(x);   // v_exp_f32 (2^x)
#else
    return exp2f(x);
#endif
}
__device__ __forceinline__ float flog2(float x) {
#if __has_builtin(__builtin_amdgcn_logf)
    return __builtin_amdgcn_logf(x);    // v_log_f32 (log2 x)
#else
    return log2f(x);
#endif
}
__device__ __forceinline__ float frcp(float x) {
#if __has_builtin(__builtin_amdgcn_rcpf)
    return __builtin_amdgcn_rcpf(x);    // v_rcp_f32 (approx; Sinkhorn self-corrects)
#else
    return 1.0f / x;
#endif
}

// ---- cross-lane helpers (proven set: DPP + ds_swizzle + shfl) ---------------
// NOTE: permlane16/32_swap REGRESSES here (rounds 2 & 8). Do not reintroduce.
#define DPP_QX1  0xB1   // quad_perm [1,0,3,2] : lane ^ 1
#define DPP_QX2  0x4E   // quad_perm [2,3,0,1] : lane ^ 2
#define DPP_ROR4 0x124  // row_ror:4 (with ror8: sums full stride-4 class in 16)
#define DPP_ROR8 0x128  // row_ror:8

template<int CTRL>
__device__ __forceinline__ float dppf(float x) {
    return __int_as_float(__builtin_amdgcn_update_dpp(
        0, __float_as_int(x), CTRL, 0xF, 0xF, true));
}
// lane ^ 16 (ds_swizzle bitmode; xor stays within each 32-lane half)
__device__ __forceinline__ float swzx16(float x) {
    return __int_as_float(__builtin_amdgcn_ds_swizzle(__float_as_int(x), 0x401F));
}

// 1-of-4 select by two loop-invariant lane predicates (3 v_cndmask)
__device__ __forceinline__ float sel4(float a0, float a1, float a2, float a3,
                                      bool c1, bool c2) {
    float x = c1 ? a1 : a0;
    float y = c1 ? a3 : a2;
    return c2 ? y : x;
}

#define NMAXN 128
#define DD    64
#define MAX_ITERS 500
#define KLOG  12
#define NITER (MAX_ITERS - KLOG)   // 488 mul iterations

// -1e5 * log2(e)  (NEG surrogate in log2 domain)
#define NEG2  (-144269.50408889634f)
// -(log2(e) / eps), eps = 1e-3 : logK2 = M * LKSC
#define LKSC  (-1442.6950408889634f)
// -(eps * ln2) : out = acc * OUTSC
#define OUTSC (-6.931471805599453e-4f)

// scalar view of the packed lk tile (c = 0..3 -> pair c>>1, half c&1)
#define LK(r, c) (((c) & 1) ? lk2[r][(c) >> 1].y : lk2[r][(c) >> 1].x)

struct SmemStage {
    float A[NMAXN * 33];   // set chunk [128][32] padded
    float B[NMAXN * 33];
    float nA[NMAXN];
    float nB[NMAXN];
};
struct SmemSink {
    float2 plog[NMAXN * 10];  // phase-1 partials (reused A then B)
    float  ulog[NMAXN];       // phase-1 u
    float  pmulA[NMAXN * 9];  // mul row partials, pair A (stride 9: 2-way banks)
    float  pmulB[NMAXN * 9];  // mul row partials, pair B
    float  gA[NMAXN];         // row factors pair A
    float  gB[NMAXN];         // row factors pair B
};
union SmemU {
    SmemStage st;
    SmemSink  sk;
    // natural size ~34.8 KiB: 256 blocks -> 1 block/CU (dispatch round-robin)
};

// ============== Load-balance prologue =======================================
// perm position p<256 holds rank p (small n1), p>=256 holds rank 511-(p-256)
// (large). Block blk takes pairs (perm[blk], perm[blk+256]) = small + large,
// so per-block work is ~uniform and the small pair gets an NR<8 template.
__global__ __launch_bounds__(512, 1)
void balance_kernel(const int* __restrict__ sz1, int* __restrict__ perm)
{
    __shared__ int keys[512];
    const int tid = threadIdx.x;
    const int k = sz1[tid];
    keys[tid] = k;
    __syncthreads();
    int r = 0;
    for (int j = 0; j < 512; ++j) {           // same-address LDS reads: broadcast
        const int kj = keys[j];
        r += (int)((kj < k) | ((kj == k) & (j < tid)));
    }
    const int p = (r < 256) ? r : (767 - r);  // bijective: [0,255] U [256,511]
    perm[p] = tid;
}

// ---- exclusive prefix offsets for pair b (512 threads, one elem each) ------
__device__ __forceinline__ void prefix_off(const int* __restrict__ sz1,
                                           const int* __restrict__ sz2,
                                           int b, int tid, int w, int lane,
                                           int* soff, int& off1, int& off2)
{
    int a1 = (tid < b) ? sz1[tid] : 0;
    int a2 = (tid < b) ? sz2[tid] : 0;
#pragma unroll
    for (int d = 1; d < 64; d <<= 1) {
        a1 += __shfl_xor(a1, d);
        a2 += __shfl_xor(a2, d);
    }
    if (lane == 0) { soff[w] = a1; soff[8 + w] = a2; }
    __syncthreads();
    off1 = 0; off2 = 0;
#pragma unroll
    for (int i = 0; i < 8; ++i) { off1 += soff[i]; off2 += soff[8 + i]; }
    __syncthreads();   // allow soff reuse
}

// ---- stage one pair into LDS, accumulate dots + norms, finalize logK2 ------
__device__ __forceinline__ void stage_pair(
    const float* __restrict__ x1, const float* __restrict__ x2,
    int off1, int off2, int n1, int n2, SmemU& sm,
    int tid, int rg, int cb32, v2f (&lk2)[8][2])
{
#pragma unroll
    for (int r = 0; r < 8; ++r)
#pragma unroll
        for (int j = 0; j < 2; ++j) { lk2[r][j].x = 0.f; lk2[r][j].y = 0.f; }

    if (tid < NMAXN) { sm.st.nA[tid] = 0.f; sm.st.nB[tid] = 0.f; }
    __syncthreads();

    const int srow = tid >> 2;  // 0..127
    const int sq   = tid & 3;   // 8-float slice of the 32-col chunk

    for (int ch = 0; ch < 2; ++ch) {
        const float* p1 = x1 + (size_t)(off1 + srow) * DD + ch * 32 + sq * 8;
        const float* p2 = x2 + (size_t)(off2 + srow) * DD + ch * 32 + sq * 8;
        const bool ok1 = srow < n1;
        const bool ok2 = srow < n2;
        float va[8], vb[8];
#pragma unroll
        for (int qq = 0; qq < 2; ++qq) {
            float4 t1 = ok1 ? ((const float4*)p1)[qq] : make_float4(0.f, 0.f, 0.f, 0.f);
            float4 t2 = ok2 ? ((const float4*)p2)[qq] : make_float4(0.f, 0.f, 0.f, 0.f);
            va[4*qq+0] = t1.x; va[4*qq+1] = t1.y; va[4*qq+2] = t1.z; va[4*qq+3] = t1.w;
            vb[4*qq+0] = t2.x; vb[4*qq+1] = t2.y; vb[4*qq+2] = t2.z; vb[4*qq+3] = t2.w;
        }
        float s1 = 0.f, s2v = 0.f;
#pragma unroll
        for (int j = 0; j < 8; ++j) {
            sm.st.A[srow * 33 + sq * 8 + j] = va[j];
            sm.st.B[srow * 33 + sq * 8 + j] = vb[j];
            s1  += va[j] * va[j];
            s2v += vb[j] * vb[j];
        }
        s1  += dppf<DPP_QX1>(s1);  s1  += dppf<DPP_QX2>(s1);
        s2v += dppf<DPP_QX1>(s2v); s2v += dppf<DPP_QX2>(s2v);
        if (sq == 0) { sm.st.nA[srow] += s1; sm.st.nB[srow] += s2v; }
        __syncthreads();
#pragma unroll 2
        for (int d = 0; d < 32; ++d) {
            float av[8];
            v2f bv2[2];
#pragma unroll
            for (int r = 0; r < 8; ++r) av[r] = sm.st.A[(rg + 16*r) * 33 + d];
            bv2[0].x = sm.st.B[(cb32     ) * 33 + d];
            bv2[0].y = sm.st.B[(cb32 + 32) * 33 + d];
            bv2[1].x = sm.st.B[(cb32 + 64) * 33 + d];
            bv2[1].y = sm.st.B[(cb32 + 96) * 33 + d];
#pragma unroll
            for (int r = 0; r < 8; ++r)
#pragma unroll
                for (int j = 0; j < 2; ++j)
                    lk2[r][j] += bv2[j] * av[r];   // v_pk_fma_f32
        }
        __syncthreads();
    }

    // logK2 = -M*log2e/eps, M = ||a||^2 + ||b||^2 - 2ab (clamped >= 0)
    {
        float rn1[8];
        v2f rn2[2];
#pragma unroll
        for (int r = 0; r < 8; ++r) rn1[r] = sm.st.nA[rg + 16*r];
        rn2[0].x = sm.st.nB[cb32];      rn2[0].y = sm.st.nB[cb32 + 32];
        rn2[1].x = sm.st.nB[cb32 + 64]; rn2[1].y = sm.st.nB[cb32 + 96];
#pragma unroll
        for (int r = 0; r < 8; ++r)
#pragma unroll
            for (int j = 0; j < 2; ++j) {
                v2f M2 = rn1[r] + rn2[j] - 2.f * lk2[r][j];
                lk2[r][j].x = fmaxf(M2.x, 0.f) * LKSC;
                lk2[r][j].y = fmaxf(M2.y, 0.f) * LKSC;
            }
    }
    __syncthreads();   // retire this pair's staging view
}

// ---- Phase 1: KLOG log-domain iterations for one pair ----------------------
__device__ __forceinline__ void phase1(
    v2f (&lk2)[8][2], int n1, int n2, SmemU& sm,
    int rg, int cg, int w, int cb32, int crow, int q,
    float (&uloc)[8], float (&v)[4])
{
    float lb[4];
    const float lbv = flog2((float)n1) - flog2((float)n2);
#pragma unroll
    for (int c = 0; c < 4; ++c)
        lb[c] = (cb32 + 32*c < n2) ? lbv : NEG2;
    const float lacrow = (crow < n1) ? 0.f : NEG2;
#pragma unroll
    for (int r = 0; r < 8; ++r) uloc[r] = 0.f;

    for (int k = 0; k < KLOG; ++k) {
        float mx[4], sc[4];
#pragma unroll
        for (int c = 0; c < 4; ++c) mx[c] = LK(0, c) + uloc[0];
#pragma unroll
        for (int r = 1; r < 8; ++r)
#pragma unroll
            for (int c = 0; c < 4; ++c)
                mx[c] = fmaxf(mx[c], LK(r, c) + uloc[r]);
#pragma unroll
        for (int c = 0; c < 4; ++c) mx[c] = fmaxf(mx[c], dppf<DPP_ROR4>(mx[c]));
#pragma unroll
        for (int c = 0; c < 4; ++c) mx[c] = fmaxf(mx[c], dppf<DPP_ROR8>(mx[c]));
#pragma unroll
        for (int c = 0; c < 4; ++c) mx[c] = fmaxf(mx[c], swzx16(mx[c]));
#pragma unroll
        for (int c = 0; c < 4; ++c) mx[c] = fmaxf(mx[c], __shfl_xor(mx[c], 32));
#pragma unroll
        for (int c = 0; c < 4; ++c) sc[c] = fexp2(LK(0, c) + uloc[0] - mx[c]);
#pragma unroll
        for (int r = 1; r < 8; ++r)
#pragma unroll
            for (int c = 0; c < 4; ++c)
                sc[c] += fexp2(LK(r, c) + uloc[r] - mx[c]);
#pragma unroll
        for (int c = 0; c < 4; ++c) sc[c] += dppf<DPP_ROR4>(sc[c]);
#pragma unroll
        for (int c = 0; c < 4; ++c) sc[c] += dppf<DPP_ROR8>(sc[c]);
#pragma unroll
        for (int c = 0; c < 4; ++c) sc[c] += swzx16(sc[c]);
#pragma unroll
        for (int c = 0; c < 4; ++c) sc[c] += __shfl_xor(sc[c], 32);
#pragma unroll
        for (int c = 0; c < 4; ++c)
            v[c] = lb[c] - (mx[c] + flog2(sc[c]));

#pragma unroll
        for (int r = 0; r < 8; ++r) {
            float mr = LK(r, 0) + v[0];
#pragma unroll
            for (int c = 1; c < 4; ++c) mr = fmaxf(mr, LK(r, c) + v[c]);
            mr = fmaxf(mr, dppf<DPP_QX1>(mr));
            mr = fmaxf(mr, dppf<DPP_QX2>(mr));
            float sr = fexp2(LK(r, 0) + v[0] - mr);
#pragma unroll
            for (int c = 1; c < 4; ++c) sr += fexp2(LK(r, c) + v[c] - mr);
            sr += dppf<DPP_QX1>(sr);
            sr += dppf<DPP_QX2>(sr);
            if ((r & 3) == cg)
                sm.sk.plog[(rg + 16*r) * 10 + w] = make_float2(mr, sr);
        }
        __syncthreads();                               // B1

        {   // cooperative combine: 4 lanes per row fold 8 (m,s) partials
            float4 t = *(const float4*)&sm.sk.plog[crow * 10 + 2 * q];
            float m = fmaxf(t.x, t.z);
            float s = t.y * fexp2(t.x - m) + t.w * fexp2(t.z - m);
            float mo = dppf<DPP_QX1>(m), so = dppf<DPP_QX1>(s);
            float mm = fmaxf(m, mo);
            s = s * fexp2(m - mm) + so * fexp2(mo - mm); m = mm;
            mo = dppf<DPP_QX2>(m); so = dppf<DPP_QX2>(s);
            mm = fmaxf(m, mo);
            s = s * fexp2(m - mm) + so * fexp2(mo - mm); m = mm;
            if (q == 0) sm.sk.ulog[crow] = lacrow - (m + flog2(s));
        }
        __syncthreads();                               // B2

#pragma unroll
        for (int r = 0; r < 8; ++r) uloc[r] = sm.sk.ulog[rg + 16*r];
    }
}

// ---- mul-phase building blocks --------------------------------------------
template<int NR>
__device__ __forceinline__ void mul_compute(
    v2f (&Q2)[NR][2], const float (&gl)[NR], v2f (&fc2)[2],
    const float (&fm)[4], float* __restrict__ pmul,
    int pstoreL, int pstoreH, bool c1, bool c2, int cg)
{
    // col sums s_c = sum_r g_r Q_rc (2x2 independent fma chains)
    v2f p0 = Q2[0][0] * gl[0];
    v2f q0 = Q2[0][1] * gl[0];
    v2f p1; p1.x = 0.f; p1.y = 0.f;
    v2f q1 = p1;
    if constexpr (NR > 1) { p1 = Q2[1][0] * gl[1]; q1 = Q2[1][1] * gl[1]; }
#pragma unroll
    for (int r = 2; r < NR; ++r) {
        if ((r & 1) == 0) { p0 += Q2[r][0] * gl[r]; q0 += Q2[r][1] * gl[r]; }
        else              { p1 += Q2[r][0] * gl[r]; q1 += Q2[r][1] * gl[r]; }
    }
    v2f s20 = p0 + p1;
    v2f s21 = q0 + q1;
    float s[4] = { s20.x, s20.y, s21.x, s21.y };
#pragma unroll
    for (int c = 0; c < 4; ++c) s[c] += dppf<DPP_ROR4>(s[c]);
#pragma unroll
    for (int c = 0; c < 4; ++c) s[c] += dppf<DPP_ROR8>(s[c]);
#pragma unroll
    for (int c = 0; c < 4; ++c) s[c] += swzx16(s[c]);
#pragma unroll
    for (int c = 0; c < 4; ++c) s[c] += __shfl_xor(s[c], 32);
    // pending column factor = fm / S (total since last fold)
    fc2[0].x = fm[0] * frcp(fmaxf(s[0], 1e-37f));
    fc2[0].y = fm[1] * frcp(fmaxf(s[1], 1e-37f));
    fc2[1].x = fm[2] * frcp(fmaxf(s[2], 1e-37f));
    fc2[1].y = fm[3] * frcp(fmaxf(s[3], 1e-37f));

    // row sums t_r = sum_c Q_rc fc_c (Q read-only); quad-uniform after DPP
    float tr[8];
#pragma unroll
    for (int r = 0; r < NR; ++r) {
        v2f t2 = Q2[r][0] * fc2[0];
        t2 += Q2[r][1] * fc2[1];     // v_pk_fma_f32
        float t = t2.x + t2.y;
        t += dppf<DPP_QX1>(t);
        t += dppf<DPP_QX2>(t);
        tr[r] = t;
    }
    float tlo = sel4(tr[0], tr[1], tr[2], tr[3], c1, c2);
    pmul[pstoreL] = tlo;
    if constexpr (NR > 4) {
        float thi = sel4(tr[4],
                         (NR > 5) ? tr[5] : tr[4],
                         (NR > 6) ? tr[6] : tr[4],
                         (NR > 7) ? tr[7] : tr[4], c1, c2);
        if constexpr (NR == 8) {
            pmul[pstoreH] = thi;
        } else {
            if (cg < NR - 4) pmul[pstoreH] = thi;
        }
    }
}

__device__ __forceinline__ void mul_combine(
    float t0, float t1, float gmask, float* __restrict__ gdst, int crow, int q)
{
    float t = t0 + t1;
    t += dppf<DPP_QX1>(t);
    t += dppf<DPP_QX2>(t);
    float gg = gmask * frcp(fmaxf(t, 1e-37f));
    if (q == 0) gdst[crow] = gg;
}

template<int NR>
__device__ __forceinline__ void fold_pair(v2f (&Q2)[NR][2], float (&gl)[NR],
                                          const v2f (&fc2)[2])
{
#pragma unroll
    for (int r = 0; r < NR; ++r) {
        Q2[r][0] *= fc2[0] * gl[r];
        Q2[r][1] *= fc2[1] * gl[r];
        gl[r] = 1.f;
    }
}

// ============ Phase 2: two pairs staggered half-iteration apart =============
// phase X: computeA(k) || combineB(k-1)  -> barrier
// phase Y: computeB(k) || combineA(k)    -> barrier
// Every LDS dependency crosses exactly one barrier; per-pair barrier count
// halves (2 -> 1 per iteration) and each combine's ds_read latency hides
// under the other pair's ~100-instr compute. Math per pair is identical to
// the round-9 kernel (same fold schedule via k = i + KLOG).
template<int NRS>
__device__ __forceinline__ void sink2(
    v2f (&lkA)[8][2], const float (&uA)[8], const float (&vA)[4],
    const float (&fmA)[4], float gmaskA,
    v2f (&lkB)[8][2], const float (&uB)[8], const float (&vB)[4],
    const float (&fmB)[4], float gmaskB,
    SmemU& sm, int rg, int cg, int w, int crow, int q,
    float& accA, float& accB)
{
    const bool c1 = (cg & 1) != 0;
    const bool c2 = (cg & 2) != 0;
    const int  pstoreL = (rg + 16 * cg) * 9 + w;
    const int  pstoreH = pstoreL + 576;
    const int  pread   = crow * 9 + 2 * q;

    // transitions: Q = exp2(lk + u + v)
    v2f QA[NRS][2];
    {
        v2f (&lk2)[8][2] = lkA;
#pragma unroll
        for (int r = 0; r < NRS; ++r)
#pragma unroll
            for (int j = 0; j < 2; ++j) {
                QA[r][j].x = fexp2(LK(r, 2*j    ) + uA[r] + vA[2*j    ]);
                QA[r][j].y = fexp2(LK(r, 2*j + 1) + uA[r] + vA[2*j + 1]);
            }
    }
    v2f QB[8][2];
    {
        v2f (&lk2)[8][2] = lkB;
#pragma unroll
        for (int r = 0; r < 8; ++r)
#pragma unroll
            for (int j = 0; j < 2; ++j) {
                QB[r][j].x = fexp2(LK(r, 2*j    ) + uB[r] + vB[2*j    ]);
                QB[r][j].y = fexp2(LK(r, 2*j + 1) + uB[r] + vB[2*j + 1]);
            }
    }

    float glA[NRS], glB[8];
#pragma unroll
    for (int r = 0; r < NRS; ++r) glA[r] = 1.f;
#pragma unroll
    for (int r = 0; r < 8; ++r) glB[r] = 1.f;
    v2f fcA[2], fcB[2];
    fcA[0].x = fcA[0].y = 0.f; fcA[1] = fcA[0];
    fcB[0] = fcA[0]; fcB[1] = fcA[0];

    for (int i = 0; i < NITER; ++i) {
        const int k = i + KLOG;
        // ---------------- phase X ----------------
        // early-issue B's partial reads (garbage at i=0, unused)
        float tB0 = sm.sk.pmulB[pread];
        float tB1 = sm.sk.pmulB[pread + 1];
        mul_compute<NRS>(QA, glA, fcA, fmA, sm.sk.pmulA, pstoreL, pstoreH, c1, c2, cg);
        if (i > 0)
            mul_combine(tB0, tB1, gmaskB, sm.sk.gB, crow, q);
        __syncthreads();                               // B1
        if (i > 0) {
#pragma unroll
            for (int r = 0; r < 8; ++r) glB[r] = sm.sk.gB[rg + 16*r];
            if (((k - 1) & 15) == 15) fold_pair<8>(QB, glB, fcB);
        }
        // ---------------- phase Y ----------------
        float tA0 = sm.sk.pmulA[pread];
        float tA1 = sm.sk.pmulA[pread + 1];
        mul_compute<8>(QB, glB, fcB, fmB, sm.sk.pmulB, pstoreL, pstoreH, c1, c2, cg);
        mul_combine(tA0, tA1, gmaskA, sm.sk.gA, crow, q);
        __syncthreads();                               // B2
#pragma unroll
        for (int r = 0; r < NRS; ++r) glA[r] = sm.sk.gA[rg + 16*r];
        if ((k & 15) == 15) fold_pair<NRS>(QA, glA, fcA);
    }

    // epilogue: B's final combine (iter 499), one extra barrier
    {
        float tB0 = sm.sk.pmulB[pread];
        float tB1 = sm.sk.pmulB[pread + 1];
        mul_combine(tB0, tB1, gmaskB, sm.sk.gB, crow, q);
        __syncthreads();
#pragma unroll
        for (int r = 0; r < 8; ++r) glB[r] = sm.sk.gB[rg + 16*r];
    }

    // accumulate: sum_ij lk_ij * (g_r Q_ij fc_c), pending factors applied
    v2f a2; a2.x = 0.f; a2.y = 0.f;
#pragma unroll
    for (int r = 0; r < NRS; ++r)
#pragma unroll
        for (int j = 0; j < 2; ++j)
            a2 += lkA[r][j] * (QA[r][j] * (fcA[j] * glA[r]));
    accA = a2.x + a2.y;
    v2f b2; b2.x = 0.f; b2.y = 0.f;
#pragma unroll
    for (int r = 0; r < 8; ++r)
#pragma unroll
        for (int j = 0; j < 2; ++j)
            b2 += lkB[r][j] * (QB[r][j] * (fcB[j] * glB[r]));
    accB = b2.x + b2.y;
}

__global__ __launch_bounds__(512, 2)
void wasserstein_kernel(const float* __restrict__ x1, const float* __restrict__ x2,
                        const int* __restrict__ sz1, const int* __restrict__ sz2,
                        const int* __restrict__ perm,
                        float* __restrict__ out)
{
    __shared__ SmemU  sm;
    __shared__ int    soff[16];
    __shared__ float  swredA[8];
    __shared__ float  swredB[8];

    const int blk  = blockIdx.x;
    const int bA   = perm[blk];         // small pair (rank blk)
    const int bB   = perm[blk + 256];   // large pair (rank 511-blk)
    const int tid  = threadIdx.x;
    const int w    = tid >> 6;
    const int lane = tid & 63;
    const int rg   = lane >> 2;
    const int cg   = lane & 3;
    const int cb32 = (w << 2) | cg;
    const int crow = tid >> 2;
    const int q    = tid & 3;

    int off1A, off2A, off1B, off2B;
    prefix_off(sz1, sz2, bA, tid, w, lane, soff, off1A, off2A);
    prefix_off(sz1, sz2, bB, tid, w, lane, soff, off1B, off2B);
    const int n1A = sz1[bA], n2A = sz2[bA];
    const int n1B = sz1[bB], n2B = sz2[bB];

    // ---- stage + logK2 for both pairs (sequential reuse of stage LDS) ----
    v2f lkA[8][2], lkB[8][2];
    stage_pair(x1, x2, off1A, off2A, n1A, n2A, sm, tid, rg, cb32, lkA);
    stage_pair(x1, x2, off1B, off2B, n1B, n2B, sm, tid, rg, cb32, lkB);

    // ---- phase 1 for both pairs (sequential reuse of plog/ulog) ----
    float uA[8], vA[4], uB[8], vB[4];
    phase1(lkA, n1A, n2A, sm, rg, cg, w, cb32, crow, q, uA, vA);
    phase1(lkB, n1B, n2B, sm, rg, cg, w, cb32, crow, q, uB, vB);

    // ---- phase 2: staggered dual-pair Sinkhorn ----
    float fmA[4], fmB[4];
    const float bmA = (float)n1A / (float)n2A;
    const float bmB = (float)n1B / (float)n2B;
#pragma unroll
    for (int c = 0; c < 4; ++c) {
        fmA[c] = (cb32 + 32*c < n2A) ? bmA : 0.f;
        fmB[c] = (cb32 + 32*c < n2B) ? bmB : 0.f;
    }
    const float gmaskA = (crow < n1A) ? 1.f : 0.f;
    const float gmaskB = (crow < n1B) ? 1.f : 0.f;

    float accA, accB;
    const int nrS = (n1A + 15) >> 4;   // small pair's row-block count (4..8)
    switch (nrS) {
        case 4:  sink2<4>(lkA, uA, vA, fmA, gmaskA, lkB, uB, vB, fmB, gmaskB,
                          sm, rg, cg, w, crow, q, accA, accB); break;
        case 5:  sink2<5>(lkA, uA, vA, fmA, gmaskA, lkB, uB, vB, fmB, gmaskB,
                          sm, rg, cg, w, crow, q, accA, accB); break;
        case 6:  sink2<6>(lkA, uA, vA, fmA, gmaskA, lkB, uB, vB, fmB, gmaskB,
                          sm, rg, cg, w, crow, q, accA, accB); break;
        case 7:  sink2<7>(lkA, uA, vA, fmA, gmaskA, lkB, uB, vB, fmB, gmaskB,
                          sm, rg, cg, w, crow, q, accA, accB); break;
        default: sink2<8>(lkA, uA, vA, fmA, gmaskA, lkB, uB, vB, fmB, gmaskB,
                          sm, rg, cg, w, crow, q, accA, accB); break;
    }

    // ---- outputs ----
    accA += dppf<DPP_QX1>(accA);
    accA += dppf<DPP_QX2>(accA);
    accA += dppf<DPP_ROR4>(accA);
    accA += dppf<DPP_ROR8>(accA);
    accA += swzx16(accA);
    accA += __shfl_xor(accA, 32);
    accB += dppf<DPP_QX1>(accB);
    accB += dppf<DPP_QX2>(accB);
    accB += dppf<DPP_ROR4>(accB);
    accB += dppf<DPP_ROR8>(accB);
    accB += swzx16(accB);
    accB += __shfl_xor(accB, 32);
    if (lane == 0) { swredA[w] = accA; swredB[w] = accB; }
    __syncthreads();
    if (tid == 0) {
        float sA = 0.f, sB = 0.f;
#pragma unroll
        for (int i = 0; i < 8; ++i) { sA += swredA[i]; sB += swredB[i]; }
        out[bA] = sA * OUTSC;
        out[bB] = sB * OUTSC;
    }
}

extern "C" void kernel_launch(void* const* d_in, const int* in_sizes, int n_in,
                              void* d_out, int out_size, void* d_ws, size_t ws_size,
                              hipStream_t stream) {
    const float* x1  = (const float*)d_in[0];
    const float* x2  = (const float*)d_in[1];
    const int*   sz1 = (const int*)d_in[2];
    const int*   sz2 = (const int*)d_in[3];
    float* out = (float*)d_out;
    int* perm = (int*)d_ws;   // 512 ints = 2 KiB of workspace

    hipLaunchKernelGGL(balance_kernel, dim3(1), dim3(512), 0, stream, sz1, perm);
    hipLaunchKernelGGL(wasserstein_kernel, dim3(256), dim3(512), 0, stream,
                       x1, x2, sz1, sz2, perm, out);
}

// Round 11
// 594.505 us; speedup vs baseline: 1.2533x; 1.2533x over previous
//
#include <hip/hip_runtime.h>

#ifndef __has_builtin
#define __has_builtin(x) 0
#endif

typedef float v2f __attribute__((ext_vector_type(2)));

__device__ __forceinline__ float fexp2(float x) {
#if __has_builtin(__builtin_amdgcn_exp2f)
    return __builtin_amdgcn_exp2f(x);   // v_exp_f32 (2^x)
#else
    return exp2f(x);
#endif
}
__device__ __forceinline__ float flog2(float x) {
#if __has_builtin(__builtin_amdgcn_logf)
    return __builtin_amdgcn_logf(x);    // v_log_f32 (log2 x)
#else
    return log2f(x);
#endif
}
__device__ __forceinline__ float frcp(float x) {
#if __has_builtin(__builtin_amdgcn_rcpf)
    return __builtin_amdgcn_rcpf(x);    // v_rcp_f32 (approx; Sinkhorn self-corrects)
#else
    return 1.0f / x;
#endif
}

// ---- cross-lane helpers (proven set: DPP + ds_swizzle + shfl) ---------------
// NOTE: permlane16/32_swap REGRESSES here (rounds 2 & 8). Do not reintroduce.
// NOTE: 1024-thr (r3) and dual-pair-stagger (r10) both regress: the sweet spot
// is 512 thr, 8x4 tiles, 2 blocks/CU = 16 waves/CU.
#define DPP_QX1  0xB1   // quad_perm [1,0,3,2] : lane ^ 1
#define DPP_QX2  0x4E   // quad_perm [2,3,0,1] : lane ^ 2
#define DPP_ROR4 0x124  // row_ror:4 (with ror8: sums full stride-4 class in 16)
#define DPP_ROR8 0x128  // row_ror:8

template<int CTRL>
__device__ __forceinline__ float dppf(float x) {
    return __int_as_float(__builtin_amdgcn_update_dpp(
        0, __float_as_int(x), CTRL, 0xF, 0xF, true));
}
// lane ^ 16 (ds_swizzle bitmode; xor stays within each 32-lane half)
__device__ __forceinline__ float swzx16(float x) {
    return __int_as_float(__builtin_amdgcn_ds_swizzle(__float_as_int(x), 0x401F));
}

// 1-of-4 select by two loop-invariant lane predicates (3 v_cndmask)
__device__ __forceinline__ float sel4(float a0, float a1, float a2, float a3,
                                      bool c1, bool c2) {
    float x = c1 ? a1 : a0;
    float y = c1 ? a3 : a2;
    return c2 ? y : x;
}

#define NMAXN 128
#define DD    64
#define MAX_ITERS 500
#define KLOG  12            // log-domain warm-up iterations

// -1e5 * log2(e)  (NEG surrogate in log2 domain)
#define NEG2  (-144269.50408889634f)
// -(log2(e) / eps), eps = 1e-3 : logK2 = M * LKSC
#define LKSC  (-1442.6950408889634f)
// -(eps * ln2) : out = acc * OUTSC
#define OUTSC (-6.931471805599453e-4f)

// scalar view of the packed lk tile (c = 0..3 -> pair c>>1, half c&1)
#define LK(r, c) (((c) & 1) ? lk2[r][(c) >> 1].y : lk2[r][(c) >> 1].x)

struct SmemStage {
    float A[NMAXN * 33];   // set1 chunk [128][32] padded
    float B[NMAXN * 33];   // set2 chunk
    float nA[NMAXN];       // row norms set1
    float nB[NMAXN];       // row norms set2
};
struct SmemSink {
    float2 plog[NMAXN * 10];  // log-phase partials: [row*10+w] -> (max,sum)
    float  ulog[NMAXN];       // log-phase u
    // mul-phase row-sum partials, stride 9: 64-lane sel4 stores 2-way banks
    float  pmul[NMAXN * 9];
    // permuted row factors: gp[(row&15)*8 + (row>>4)] for rows 0..127, so a
    // thread's 8 rows (rg+16r) are CONTIGUOUS -> 2x ds_read_b128 reload.
    // Slots 128..509 are a dummy sink for the unconditional combine store.
    float  gp[512];
};
union SmemU {
    SmemStage st;
    SmemSink  sk;
    // occupancy clamp: 60 KiB -> exactly 2 blocks/CU; 512 blocks = 512 slots.
    char force[61440];
};

// ============== Load-balance prologue =======================================
// Work per pair ~ NR = ceil(n1/16). Blocks b and b+256 co-reside on a CU
// (in-order dispatch, round-robin over 8 XCDs x 32 CUs, 2 slots/CU). Place
// rank r (ascending n1) at position r for r<256 and 767-r for r>=256, so
// positions p and p+256 carry ranks r and 511-r -> per-CU work sums ~const.
__global__ __launch_bounds__(512, 1)
void balance_kernel(const int* __restrict__ sz1, int* __restrict__ perm)
{
    __shared__ int keys[512];
    const int tid = threadIdx.x;
    const int k = sz1[tid];
    keys[tid] = k;
    __syncthreads();
    int r = 0;
    for (int j = 0; j < 512; ++j) {           // same-address LDS reads: broadcast
        const int kj = keys[j];
        r += (int)((kj < k) | ((kj == k) & (j < tid)));
    }
    const int p = (r < 256) ? r : (767 - r);  // bijective: [0,255] U [256,511]
    perm[p] = tid;
}

// ================= Phase 2 (templated on NR = ceil(n1/16)) ==================
// Multiplicative Sinkhorn with lazy row factor g AND lazy column factor fc.
// fc_new = fm/S directly (telescoping); both factors fold into Q every 16
// iters to bound drift. Rows r >= NR are exact zeros, skipped everywhere.
// Row-partial stores via quad-uniform sel4 (2 stores replace 8 exec-masked).
// Combine store: gg is quad-uniform after the 2 DPP adds, so ALL lanes store
// unconditionally -- q==0 lanes to the permuted slot, q!=0 to dummy slots
// (loop-invariant address, no exec-mask juggling).
template<int NR>
__device__ __forceinline__ float sink_mul(
    v2f (&lk2)[8][2], const float (&uloc)[8], const float (&v)[4],
    const float (&fm)[4], float gmask,
    SmemU& sm, int rg, int cg, int w, int crow, int q)
{
    const bool c1 = (cg & 1) != 0;
    const bool c2 = (cg & 2) != 0;
    const int  pstoreL = (rg + 16 * cg) * 9 + w;    // row rg+16*cg
    const int  pstoreH = pstoreL + 576;             // row rg+16*cg+64 (*9)
    const int  pread   = crow * 9 + 2 * q;
    // permuted-g store slot (q==0: real; q!=0: distinct dummy >=128)
    const int  gsto = (q == 0) ? (((crow & 15) << 3) | (crow >> 4))
                               : (128 + crow * 3 + (q - 1));
    const int  grd  = rg << 3;                      // this thread's 8 rows

    // transition: Q = exp2(lk + u + v), constant between folds
    v2f Q2[NR][2];
#pragma unroll
    for (int r = 0; r < NR; ++r)
#pragma unroll
        for (int j = 0; j < 2; ++j) {
            Q2[r][j].x = fexp2(LK(r, 2*j    ) + uloc[r] + v[2*j    ]);
            Q2[r][j].y = fexp2(LK(r, 2*j + 1) + uloc[r] + v[2*j + 1]);
        }
    float gl[NR];
#pragma unroll
    for (int r = 0; r < NR; ++r) gl[r] = 1.f;
    v2f fc2[2];
    fc2[0].x = fc2[0].y = 0.f;
    fc2[1] = fc2[0];

    for (int k = KLOG; k < MAX_ITERS; ++k) {
        // --- col sums s_c = sum_r g_r Q_rc (2x2 independent fma chains) ---
        v2f p0 = Q2[0][0] * gl[0];
        v2f q0 = Q2[0][1] * gl[0];
        v2f p1; p1.x = 0.f; p1.y = 0.f;
        v2f q1 = p1;
        if constexpr (NR > 1) { p1 = Q2[1][0] * gl[1]; q1 = Q2[1][1] * gl[1]; }
#pragma unroll
        for (int r = 2; r < NR; ++r) {
            if ((r & 1) == 0) { p0 += Q2[r][0] * gl[r]; q0 += Q2[r][1] * gl[r]; }
            else              { p1 += Q2[r][0] * gl[r]; q1 += Q2[r][1] * gl[r]; }
        }
        v2f s20 = p0 + p1;
        v2f s21 = q0 + q1;
        float s[4] = { s20.x, s20.y, s21.x, s21.y };
#pragma unroll
        for (int c = 0; c < 4; ++c) s[c] += dppf<DPP_ROR4>(s[c]);
#pragma unroll
        for (int c = 0; c < 4; ++c) s[c] += dppf<DPP_ROR8>(s[c]);
#pragma unroll
        for (int c = 0; c < 4; ++c) s[c] += swzx16(s[c]);
#pragma unroll
        for (int c = 0; c < 4; ++c) s[c] += __shfl_xor(s[c], 32);
        // pending column factor = fm / S (total since last fold)
        fc2[0].x = fm[0] * frcp(fmaxf(s[0], 1e-37f));
        fc2[0].y = fm[1] * frcp(fmaxf(s[1], 1e-37f));
        fc2[1].x = fm[2] * frcp(fmaxf(s[2], 1e-37f));
        fc2[1].y = fm[3] * frcp(fmaxf(s[3], 1e-37f));

        // --- row sums t_r = sum_c Q_rc fc_c (Q read-only) ---
        float tr[8];
#pragma unroll
        for (int r = 0; r < NR; ++r) {
            v2f t2 = Q2[r][0] * fc2[0];
            t2 += Q2[r][1] * fc2[1];     // v_pk_fma_f32
            float t = t2.x + t2.y;
            t += dppf<DPP_QX1>(t);
            t += dppf<DPP_QX2>(t);
            tr[r] = t;                   // uniform across the quad
        }
        {   // lane cg stores rows cg and cg+4 (2 unconditional-ish stores)
            float tlo = sel4(tr[0], tr[1], tr[2], tr[3], c1, c2);
            sm.sk.pmul[pstoreL] = tlo;
            if constexpr (NR > 4) {
                float thi = sel4(tr[4],
                                 (NR > 5) ? tr[5] : tr[4],
                                 (NR > 6) ? tr[6] : tr[4],
                                 (NR > 7) ? tr[7] : tr[4], c1, c2);
                if constexpr (NR == 8) {
                    sm.sk.pmul[pstoreH] = thi;
                } else {
                    if (cg < NR - 4) sm.sk.pmul[pstoreH] = thi;
                }
            }
        }
        __syncthreads();                               // B1

        {   // cooperative combine: 4 lanes per row fold 8 partials
            float t0 = sm.sk.pmul[pread];
            float t1 = sm.sk.pmul[pread + 1];
            float t = t0 + t1;
            t += dppf<DPP_QX1>(t);
            t += dppf<DPP_QX2>(t);
            float gg = gmask * frcp(fmaxf(t, 1e-37f));
            sm.sk.gp[gsto] = gg;         // unconditional (dummy sink for q!=0)
        }
        __syncthreads();                               // B2

        {   // vector reload: thread's 8 rows contiguous in gp
            float4 ga = *(const float4*)&sm.sk.gp[grd];
            gl[0] = ga.x;
            if constexpr (NR > 1) gl[1] = ga.y;
            if constexpr (NR > 2) gl[2] = ga.z;
            if constexpr (NR > 3) gl[3] = ga.w;
            if constexpr (NR > 4) {
                float4 gb = *(const float4*)&sm.sk.gp[grd + 4];
                gl[4] = gb.x;
                if constexpr (NR > 5) gl[5] = gb.y;
                if constexpr (NR > 6) gl[6] = gb.z;
                if constexpr (NR > 7) gl[7] = gb.w;
            }
        }

        // fold both pending factors into Q (bounds drift; k=499 is NOT a fold
        // iteration with these constants, so epilogue factors stay pending)
        if ((k & 15) == 15) {
#pragma unroll
            for (int r = 0; r < NR; ++r) {
                Q2[r][0] *= fc2[0] * gl[r];
                Q2[r][1] *= fc2[1] * gl[r];
                gl[r] = 1.f;
            }
        }
    }

    // ---- epilogue accumulate: sum_ij lk_ij * (g_r Q_ij fc_c) ----
    v2f acc2; acc2.x = 0.f; acc2.y = 0.f;
#pragma unroll
    for (int r = 0; r < NR; ++r)
#pragma unroll
        for (int j = 0; j < 2; ++j)
            acc2 += lk2[r][j] * (Q2[r][j] * (fc2[j] * gl[r]));
    return acc2.x + acc2.y;
}

__global__ __launch_bounds__(512, 4)
void wasserstein_kernel(const float* __restrict__ x1, const float* __restrict__ x2,
                        const int* __restrict__ sz1, const int* __restrict__ sz2,
                        const int* __restrict__ perm,
                        float* __restrict__ out)
{
    __shared__ SmemU  sm;
    __shared__ int    soff[16];
    __shared__ float  swred[8];

    const int b    = perm[blockIdx.x];   // load-balanced pair assignment
    const int tid  = threadIdx.x;
    const int w    = tid >> 6;        // wave 0..7
    const int lane = tid & 63;
    const int rg   = lane >> 2;       // 0..15 : rows rg + 16*r   (r = 0..7)
    const int cg   = lane & 3;        // with w: cols (w*4+cg) + 32*c (c = 0..3)
    const int cb32 = (w << 2) | cg;   // 0..31

    // ---- exclusive prefix sums of sizes (512 threads: one element each) ----
    int a1 = (tid < b) ? sz1[tid] : 0;
    int a2 = (tid < b) ? sz2[tid] : 0;
#pragma unroll
    for (int d = 1; d < 64; d <<= 1) {
        a1 += __shfl_xor(a1, d);
        a2 += __shfl_xor(a2, d);
    }
    if (lane == 0) { soff[w] = a1; soff[8 + w] = a2; }
    if (tid < NMAXN) { sm.st.nA[tid] = 0.f; sm.st.nB[tid] = 0.f; }
    __syncthreads();
    int off1 = 0, off2 = 0;
#pragma unroll
    for (int i = 0; i < 8; ++i) { off1 += soff[i]; off2 += soff[8 + i]; }
    const int n1 = sz1[b];
    const int n2 = sz2[b];

    // ---- stage sets in D-chunks of 32, accumulate dots + norms ----
    v2f lk2[8][2];   // packed over col pairs; starts as dot acc, becomes logK2
#pragma unroll
    for (int r = 0; r < 8; ++r)
#pragma unroll
        for (int j = 0; j < 2; ++j) { lk2[r][j].x = 0.f; lk2[r][j].y = 0.f; }

    const int srow = tid >> 2;  // 0..127
    const int sq   = tid & 3;   // 8-float slice of the 32-col chunk

    for (int ch = 0; ch < 2; ++ch) {
        const float* p1 = x1 + (size_t)(off1 + srow) * DD + ch * 32 + sq * 8;
        const float* p2 = x2 + (size_t)(off2 + srow) * DD + ch * 32 + sq * 8;
        const bool ok1 = srow < n1;
        const bool ok2 = srow < n2;
        float va[8], vb[8];
#pragma unroll
        for (int qq = 0; qq < 2; ++qq) {
            float4 t1 = ok1 ? ((const float4*)p1)[qq] : make_float4(0.f, 0.f, 0.f, 0.f);
            float4 t2 = ok2 ? ((const float4*)p2)[qq] : make_float4(0.f, 0.f, 0.f, 0.f);
            va[4*qq+0] = t1.x; va[4*qq+1] = t1.y; va[4*qq+2] = t1.z; va[4*qq+3] = t1.w;
            vb[4*qq+0] = t2.x; vb[4*qq+1] = t2.y; vb[4*qq+2] = t2.z; vb[4*qq+3] = t2.w;
        }
        float s1 = 0.f, s2v = 0.f;
#pragma unroll
        for (int j = 0; j < 8; ++j) {
            sm.st.A[srow * 33 + sq * 8 + j] = va[j];
            sm.st.B[srow * 33 + sq * 8 + j] = vb[j];
            s1  += va[j] * va[j];
            s2v += vb[j] * vb[j];
        }
        s1  += dppf<DPP_QX1>(s1);  s1  += dppf<DPP_QX2>(s1);
        s2v += dppf<DPP_QX1>(s2v); s2v += dppf<DPP_QX2>(s2v);
        if (sq == 0) { sm.st.nA[srow] += s1; sm.st.nB[srow] += s2v; }
        __syncthreads();
#pragma unroll 2
        for (int d = 0; d < 32; ++d) {
            float av[8];
            v2f bv2[2];
#pragma unroll
            for (int r = 0; r < 8; ++r) av[r] = sm.st.A[(rg + 16*r) * 33 + d];
            bv2[0].x = sm.st.B[(cb32     ) * 33 + d];
            bv2[0].y = sm.st.B[(cb32 + 32) * 33 + d];
            bv2[1].x = sm.st.B[(cb32 + 64) * 33 + d];
            bv2[1].y = sm.st.B[(cb32 + 96) * 33 + d];
#pragma unroll
            for (int r = 0; r < 8; ++r)
#pragma unroll
                for (int j = 0; j < 2; ++j)
                    lk2[r][j] += bv2[j] * av[r];   // v_pk_fma_f32
        }
        __syncthreads();
    }

    // logK2 = -M*log2e/eps, M = ||a||^2 + ||b||^2 - 2ab (clamped >= 0)
    float lb[4];
    const float lbv = flog2((float)n1) - flog2((float)n2);
    {
        float rn1[8];
        v2f rn2[2];
#pragma unroll
        for (int r = 0; r < 8; ++r) rn1[r] = sm.st.nA[rg + 16*r];
        rn2[0].x = sm.st.nB[cb32];      rn2[0].y = sm.st.nB[cb32 + 32];
        rn2[1].x = sm.st.nB[cb32 + 64]; rn2[1].y = sm.st.nB[cb32 + 96];
#pragma unroll
        for (int r = 0; r < 8; ++r)
#pragma unroll
            for (int j = 0; j < 2; ++j) {
                v2f M2 = rn1[r] + rn2[j] - 2.f * lk2[r][j];
                lk2[r][j].x = fmaxf(M2.x, 0.f) * LKSC;
                lk2[r][j].y = fmaxf(M2.y, 0.f) * LKSC;
            }
#pragma unroll
        for (int c = 0; c < 4; ++c)
            lb[c] = (cb32 + 32*c < n2) ? lbv : NEG2;
    }
    __syncthreads();   // retire staging view of the union

    const int   crow   = tid >> 2;                  // coop-combine row 0..127
    const int   q      = tid & 3;
    const float lacrow = (crow < n1) ? 0.f : NEG2;

    float uloc[8], v[4];
#pragma unroll
    for (int r = 0; r < 8; ++r) uloc[r] = 0.f;

    // ================= Phase 1: KLOG log-domain iterations =================
    for (int k = 0; k < KLOG; ++k) {
        float mx[4], sc[4];
#pragma unroll
        for (int c = 0; c < 4; ++c) mx[c] = LK(0, c) + uloc[0];
#pragma unroll
        for (int r = 1; r < 8; ++r)
#pragma unroll
            for (int c = 0; c < 4; ++c)
                mx[c] = fmaxf(mx[c], LK(r, c) + uloc[r]);
#pragma unroll
        for (int c = 0; c < 4; ++c) mx[c] = fmaxf(mx[c], dppf<DPP_ROR4>(mx[c]));
#pragma unroll
        for (int c = 0; c < 4; ++c) mx[c] = fmaxf(mx[c], dppf<DPP_ROR8>(mx[c]));
#pragma unroll
        for (int c = 0; c < 4; ++c) mx[c] = fmaxf(mx[c], swzx16(mx[c]));
#pragma unroll
        for (int c = 0; c < 4; ++c) mx[c] = fmaxf(mx[c], __shfl_xor(mx[c], 32));
#pragma unroll
        for (int c = 0; c < 4; ++c) sc[c] = fexp2(LK(0, c) + uloc[0] - mx[c]);
#pragma unroll
        for (int r = 1; r < 8; ++r)
#pragma unroll
            for (int c = 0; c < 4; ++c)
                sc[c] += fexp2(LK(r, c) + uloc[r] - mx[c]);
#pragma unroll
        for (int c = 0; c < 4; ++c) sc[c] += dppf<DPP_ROR4>(sc[c]);
#pragma unroll
        for (int c = 0; c < 4; ++c) sc[c] += dppf<DPP_ROR8>(sc[c]);
#pragma unroll
        for (int c = 0; c < 4; ++c) sc[c] += swzx16(sc[c]);
#pragma unroll
        for (int c = 0; c < 4; ++c) sc[c] += __shfl_xor(sc[c], 32);
#pragma unroll
        for (int c = 0; c < 4; ++c)
            v[c] = lb[c] - (mx[c] + flog2(sc[c]));

#pragma unroll
        for (int r = 0; r < 8; ++r) {
            float mr = LK(r, 0) + v[0];
#pragma unroll
            for (int c = 1; c < 4; ++c) mr = fmaxf(mr, LK(r, c) + v[c]);
            mr = fmaxf(mr, dppf<DPP_QX1>(mr));
            mr = fmaxf(mr, dppf<DPP_QX2>(mr));
            float sr = fexp2(LK(r, 0) + v[0] - mr);
#pragma unroll
            for (int c = 1; c < 4; ++c) sr += fexp2(LK(r, c) + v[c] - mr);
            sr += dppf<DPP_QX1>(sr);
            sr += dppf<DPP_QX2>(sr);
            if ((r & 3) == cg)
                sm.sk.plog[(rg + 16*r) * 10 + w] = make_float2(mr, sr);
        }
        __syncthreads();                               // B1

        {   // cooperative combine: 4 lanes per row fold 8 (m,s) partials
            float4 t = *(const float4*)&sm.sk.plog[crow * 10 + 2 * q];
            float m = fmaxf(t.x, t.z);
            float s = t.y * fexp2(t.x - m) + t.w * fexp2(t.z - m);
            float mo = dppf<DPP_QX1>(m), so = dppf<DPP_QX1>(s);
            float mm = fmaxf(m, mo);
            s = s * fexp2(m - mm) + so * fexp2(mo - mm); m = mm;
            mo = dppf<DPP_QX2>(m); so = dppf<DPP_QX2>(s);
            mm = fmaxf(m, mo);
            s = s * fexp2(m - mm) + so * fexp2(mo - mm); m = mm;
            if (q == 0) sm.sk.ulog[crow] = lacrow - (m + flog2(s));
        }
        __syncthreads();                               // B2

#pragma unroll
        for (int r = 0; r < 8; ++r) uloc[r] = sm.sk.ulog[rg + 16*r];
    }

    // ================= Phase 2 dispatch (block-uniform on n1) ==============
    const float bmulv = (float)n1 / (float)n2;   // beta for valid cols
    float fm[4];
#pragma unroll
    for (int c = 0; c < 4; ++c)
        fm[c] = (cb32 + 32*c < n2) ? bmulv : 0.f;
    const float gmask = (crow < n1) ? 1.f : 0.f;

    float acc;
    const int nr = (n1 + 15) >> 4;   // 4..8
    switch (nr) {
        case 4:  acc = sink_mul<4>(lk2, uloc, v, fm, gmask, sm, rg, cg, w, crow, q); break;
        case 5:  acc = sink_mul<5>(lk2, uloc, v, fm, gmask, sm, rg, cg, w, crow, q); break;
        case 6:  acc = sink_mul<6>(lk2, uloc, v, fm, gmask, sm, rg, cg, w, crow, q); break;
        case 7:  acc = sink_mul<7>(lk2, uloc, v, fm, gmask, sm, rg, cg, w, crow, q); break;
        default: acc = sink_mul<8>(lk2, uloc, v, fm, gmask, sm, rg, cg, w, crow, q); break;
    }

    // ---- output: out_b = OUTSC * block-sum(acc) ----
    acc += dppf<DPP_QX1>(acc);
    acc += dppf<DPP_QX2>(acc);
    acc += dppf<DPP_ROR4>(acc);
    acc += dppf<DPP_ROR8>(acc);
    acc += swzx16(acc);
    acc += __shfl_xor(acc, 32);
    if (lane == 0) swred[w] = acc;
    __syncthreads();
    if (tid == 0) {
        float s = 0.f;
#pragma unroll
        for (int i = 0; i < 8; ++i) s += swred[i];
        out[b] = s * OUTSC;
    }
}

extern "C" void kernel_launch(void* const* d_in, const int* in_sizes, int n_in,
                              void* d_out, int out_size, void* d_ws, size_t ws_size,
                              hipStream_t stream) {
    const float* x1  = (const float*)d_in[0];
    const float* x2  = (const float*)d_in[1];
    const int*   sz1 = (const int*)d_in[2];
    const int*   sz2 = (const int*)d_in[3];
    float* out = (float*)d_out;
    int* perm = (int*)d_ws;   // 512 ints = 2 KiB of workspace

    hipLaunchKernelGGL(balance_kernel, dim3(1), dim3(512), 0, stream, sz1, perm);
    hipLaunchKernelGGL(wasserstein_kernel, dim3(512), dim3(512), 0, stream,
                       x1, x2, sz1, sz2, perm, out);
}